// Round 6
// baseline (881.442 us; speedup 1.0000x reference)
//
#include <hip/hip_runtime.h>
#include <math.h>

#define VOCAB 32000
#define EM    256
#define UNITS 512
#define BATCH 64
#define TSTEP 16
#define G4    (4*UNITS)      // 2048
#define KFLAT (TSTEP*UNITS)  // 8192
#define KSPLIT 4             // K-split for logits GEMM

typedef __bf16 bf16x8 __attribute__((ext_vector_type(8)));
typedef float  f32x4  __attribute__((ext_vector_type(4)));
union FragU { unsigned short u[8]; bf16x8 v; };

// ---- module-scope scratch (all fully rewritten every call) ----
__device__ __align__(16) float g_xz [TSTEP*BATCH*G4];      // 8 MB  [t][b][col]
__device__ __align__(16) float g_ht0[UNITS*BATCH];         // h^T [512][64]
__device__ __align__(16) float g_ht1[UNITS*BATCH];
__device__ __align__(16) float g_c0 [BATCH*UNITS];
__device__ __align__(16) float g_c1 [BATCH*UNITS];
__device__ __align__(16) unsigned short g_Ah[BATCH*KFLAT]; // flat hi (bf16) 1 MB
__device__ __align__(16) unsigned short g_Al[BATCH*KFLAT]; // flat lo (bf16) 1 MB
__device__ __align__(16) float g_part[KSPLIT*BATCH*VOCAB]; // 32.8 MB partial logits

__device__ __forceinline__ float sigmoidf_(float x) {
    return 1.0f / (1.0f + expf(-x));
}
__device__ __forceinline__ unsigned short f2bf(float f) {   // fp32 -> bf16 RNE
    unsigned u = __float_as_uint(f);
    return (unsigned short)((u + 0x7fffu + ((u >> 16) & 1u)) >> 16);
}
__device__ __forceinline__ float bf2f(unsigned short h) {
    return __uint_as_float((unsigned)h << 16);
}

// enc_h [64][512] -> g_ht0 [512][64]
__global__ __launch_bounds__(256) void transpose_h_kernel(const float* __restrict__ src)
{
    int i = blockIdx.x * 256 + threadIdx.x;   // 32768
    int b = i >> 9, u = i & 511;
    g_ht0[u*BATCH + b] = src[i];
}

// xz[t][b][col] = bias[col] + emb[inputs[b][t]][:] @ Wx[:,col]
// grid (8, 256) x 256 thr: 4 rows (of 1024) x 256 cols per block.
__global__ __launch_bounds__(256) void xz_kernel(
    const int* __restrict__ inputs, const float* __restrict__ emb,
    const float* __restrict__ Wx, const float* __restrict__ bias)
{
    const int col = blockIdx.x * 256 + threadIdx.x;
    const int r0  = blockIdx.y * 4;
    const float* e[4];
    #pragma unroll
    for (int i = 0; i < 4; ++i) {
        int r = r0 + i, t = r >> 6, b = r & 63;
        e[i] = emb + (size_t)inputs[b*TSTEP + t]*EM;
    }
    float a0 = bias[col], a1 = a0, a2 = a0, a3 = a0;
    #pragma unroll 4
    for (int k = 0; k < EM; ++k) {
        float w = Wx[(size_t)k*G4 + col];
        a0 = fmaf(e[0][k], w, a0);
        a1 = fmaf(e[1][k], w, a1);
        a2 = fmaf(e[2][k], w, a2);
        a3 = fmaf(e[3][k], w, a3);
    }
    g_xz[(size_t)(r0+0)*G4 + col] = a0;
    g_xz[(size_t)(r0+1)*G4 + col] = a1;
    g_xz[(size_t)(r0+2)*G4 + col] = a2;
    g_xz[(size_t)(r0+3)*G4 + col] = a3;
}

// One LSTM step: z = xz_t + h @ Wh, gates, update c/h.
// grid (16 u-tiles, 16 b-tiles) = 256 blocks x 256 thr.
__global__ __launch_bounds__(256) void lstm_step_kernel(
    const float* __restrict__ Wh, const float* __restrict__ enc_c, int t)
{
    const float* h_in  = (t & 1) ? g_ht1 : g_ht0;
    float*       h_out = (t & 1) ? g_ht0 : g_ht1;
    const float* c_in  = (t == 0) ? enc_c : ((t & 1) ? g_c0 : g_c1);
    float*       c_out = (t & 1) ? g_c1 : g_c0;

    __shared__ float zp[2][128][4];
    const int tid  = threadIdx.x;
    const int ci   = tid & 127, kh = tid >> 7;
    const int gate = ci >> 5, ul = ci & 31;
    const int u0   = blockIdx.x * 32;
    const int b0   = blockIdx.y * 4;
    const int col  = gate*UNITS + u0 + ul;

    float a0, a1, a2, a3;
    if (kh == 0) {
        const float* xz = g_xz + ((size_t)t*BATCH + b0)*G4 + col;
        a0 = xz[0]; a1 = xz[G4]; a2 = xz[2*G4]; a3 = xz[3*G4];
    } else {
        a0 = a1 = a2 = a3 = 0.f;
    }
    const int k0 = kh * 256;
    #pragma unroll 4
    for (int k = k0; k < k0 + 256; ++k) {
        float w = Wh[(size_t)k*G4 + col];
        const float4 hv = *reinterpret_cast<const float4*>(h_in + (size_t)k*BATCH + b0);
        a0 = fmaf(hv.x, w, a0);
        a1 = fmaf(hv.y, w, a1);
        a2 = fmaf(hv.z, w, a2);
        a3 = fmaf(hv.w, w, a3);
    }
    zp[kh][ci][0] = a0; zp[kh][ci][1] = a1;
    zp[kh][ci][2] = a2; zp[kh][ci][3] = a3;
    __syncthreads();

    if (tid < 128) {
        const int bl = tid >> 5, u2 = tid & 31;
        const int b = b0 + bl, u = u0 + u2;
        float zi = zp[0][0*32 + u2][bl] + zp[1][0*32 + u2][bl];
        float zf = zp[0][1*32 + u2][bl] + zp[1][1*32 + u2][bl];
        float zg = zp[0][2*32 + u2][bl] + zp[1][2*32 + u2][bl];
        float zo = zp[0][3*32 + u2][bl] + zp[1][3*32 + u2][bl];
        float c = sigmoidf_(zf) * c_in[(size_t)b*UNITS + u] + sigmoidf_(zi) * sigmoidf_(zg);
        float h = sigmoidf_(zo) * sigmoidf_(c);
        c_out[(size_t)b*UNITS + u] = c;
        h_out[(size_t)u*BATCH + b] = h;
        unsigned short hh = f2bf(h);
        size_t ai = (size_t)b*KFLAT + t*UNITS + u;
        g_Ah[ai] = hh;
        g_Al[ai] = f2bf(h - bf2f(hh));
    }
}

// Partial logits via bf16x3-split MFMA.
// grid (250 n-blocks, 4 k-splits) x 256 thr (4 waves).
// Wave: 64x32 output tile (4 M-subtiles x 2 N-tiles), K-range 2048.
// fp32 ~= hi*hi + lo*hi + hi*lo  (lo*lo dropped, 2^-18 relative).
// B is loaded/split one N-tile at a time to keep live VGPRs ~<100 (round-5
// version held both N-tiles live under a 128-VGPR cap -> spill risk).
__global__ __launch_bounds__(256, 4) void logits_mfma_kernel(
    const float* __restrict__ Wout)
{
    const int tid = threadIdx.x;
    const int wv  = tid >> 6, l = tid & 63;
    const int r   = l & 15, g = l >> 4;       // frag row = r, k-group = g
    const int g8  = g * 8;
    const int n0  = blockIdx.x * 128 + wv * 32;
    const int k0  = blockIdx.y * (KFLAT / KSPLIT);   // 2048-sized K range

    f32x4 acc[4][2];
    #pragma unroll
    for (int ms = 0; ms < 4; ++ms)
        #pragma unroll
        for (int nt = 0; nt < 2; ++nt)
            acc[ms][nt] = (f32x4){0.f, 0.f, 0.f, 0.f};

    for (int kk = 0; kk < KFLAT / KSPLIT; kk += 32) {
        const int kbase = k0 + kk + g8;
        // --- A fragments (shared across both N-tiles) ---
        FragU ah[4], al[4];
        #pragma unroll
        for (int ms = 0; ms < 4; ++ms) {
            size_t aoff = (size_t)(ms*16 + r)*KFLAT + kbase;
            ah[ms].v = *reinterpret_cast<const bf16x8*>(g_Ah + aoff);
            al[ms].v = *reinterpret_cast<const bf16x8*>(g_Al + aoff);
        }
        // --- per N-tile: gather B column slice, split, 12 MFMAs ---
        #pragma unroll
        for (int nt = 0; nt < 2; ++nt) {
            const float* wB = Wout + (size_t)kbase * VOCAB + n0 + nt*16 + r;
            float w[8];
            #pragma unroll
            for (int j = 0; j < 8; ++j)
                w[j] = __builtin_nontemporal_load(wB + (size_t)j * VOCAB);
            FragU bh, bl;
            #pragma unroll
            for (int j = 0; j < 8; ++j) {
                unsigned short hi = f2bf(w[j]);
                bh.u[j] = hi;
                bl.u[j] = f2bf(w[j] - bf2f(hi));
            }
            #pragma unroll
            for (int ms = 0; ms < 4; ++ms)
                acc[ms][nt] = __builtin_amdgcn_mfma_f32_16x16x32_bf16(ah[ms].v, bh.v, acc[ms][nt], 0, 0, 0);
            #pragma unroll
            for (int ms = 0; ms < 4; ++ms)
                acc[ms][nt] = __builtin_amdgcn_mfma_f32_16x16x32_bf16(al[ms].v, bh.v, acc[ms][nt], 0, 0, 0);
            #pragma unroll
            for (int ms = 0; ms < 4; ++ms)
                acc[ms][nt] = __builtin_amdgcn_mfma_f32_16x16x32_bf16(ah[ms].v, bl.v, acc[ms][nt], 0, 0, 0);
        }
    }
    // --- write partial: C row = (lane>>4)*4 + reg, col = lane&15 ---
    float* pp = g_part + (size_t)blockIdx.y * BATCH * VOCAB;
    #pragma unroll
    for (int ms = 0; ms < 4; ++ms) {
        #pragma unroll
        for (int nt = 0; nt < 2; ++nt) {
            #pragma unroll
            for (int j = 0; j < 4; ++j) {
                int m = ms*16 + g*4 + j;
                pp[(size_t)m*VOCAB + n0 + nt*16 + r] = acc[ms][nt][j];
            }
        }
    }
}

// Combine K-split partials + bias, then row softmax. One block per row.
__global__ __launch_bounds__(1024) void combine_softmax_kernel(
    const float* __restrict__ bout, float* __restrict__ out)
{
    const int m = blockIdx.x;
    const int tid = threadIdx.x;
    const int wid = tid >> 6, lane = tid & 63;
    __shared__ float red[16];
    float* po = out + (size_t)m * VOCAB;

    float mx = -3.0e38f;
    for (int n = tid; n < VOCAB; n += 1024) {
        float v = g_part[(size_t)0*BATCH*VOCAB + (size_t)m*VOCAB + n]
                + g_part[(size_t)1*BATCH*VOCAB + (size_t)m*VOCAB + n]
                + g_part[(size_t)2*BATCH*VOCAB + (size_t)m*VOCAB + n]
                + g_part[(size_t)3*BATCH*VOCAB + (size_t)m*VOCAB + n]
                + bout[n];
        po[n] = v;
        mx = fmaxf(mx, v);
    }
    #pragma unroll
    for (int o = 32; o; o >>= 1) mx = fmaxf(mx, __shfl_xor(mx, o));
    if (lane == 0) red[wid] = mx;
    __syncthreads();
    mx = red[0];
    #pragma unroll
    for (int i = 1; i < 16; ++i) mx = fmaxf(mx, red[i]);
    __syncthreads();

    float s = 0.f;
    for (int n = tid; n < VOCAB; n += 1024) {
        float e = expf(po[n] - mx);
        po[n] = e;
        s += e;
    }
    #pragma unroll
    for (int o = 32; o; o >>= 1) s += __shfl_xor(s, o);
    if (lane == 0) red[wid] = s;
    __syncthreads();
    s = 0.f;
    #pragma unroll
    for (int i = 0; i < 16; ++i) s += red[i];
    float inv = 1.0f / s;

    for (int n = tid; n < VOCAB; n += 1024) po[n] *= inv;
}

extern "C" void kernel_launch(void* const* d_in, const int* in_sizes, int n_in,
                              void* d_out, int out_size, void* d_ws, size_t ws_size,
                              hipStream_t stream) {
    const int*   inputs = (const int*)  d_in[0];
    const float* enc_h  = (const float*)d_in[1];
    const float* enc_c  = (const float*)d_in[2];
    const float* emb    = (const float*)d_in[3];
    const float* Wx     = (const float*)d_in[4];
    const float* Wh     = (const float*)d_in[5];
    const float* bvec   = (const float*)d_in[6];
    const float* Wout   = (const float*)d_in[7];
    const float* bout   = (const float*)d_in[8];
    float* out = (float*)d_out;
    (void)d_ws; (void)ws_size; (void)in_sizes; (void)n_in; (void)out_size;

    transpose_h_kernel<<<128, 256, 0, stream>>>(enc_h);
    xz_kernel<<<dim3(8, 256), 256, 0, stream>>>(inputs, emb, Wx, bvec);

    for (int t = 0; t < TSTEP; ++t)
        lstm_step_kernel<<<dim3(16, 16), 256, 0, stream>>>(Wh, enc_c, t);

    logits_mfma_kernel<<<dim3(250, KSPLIT), 256, 0, stream>>>(Wout);
    combine_softmax_kernel<<<64, 1024, 0, stream>>>(bout, out);
}

// Round 7
// 846.590 us; speedup vs baseline: 1.0412x; 1.0412x over previous
//
#include <hip/hip_runtime.h>
#include <math.h>

#define VOCAB 32000
#define EM    256
#define UNITS 512
#define BATCH 64
#define TSTEP 16
#define G4    (4*UNITS)      // 2048
#define KFLAT (TSTEP*UNITS)  // 8192
#define KSPLIT 4             // K-split for logits GEMM
#define KR    (KFLAT/KSPLIT) // 2048 per split

typedef __bf16 bf16x8 __attribute__((ext_vector_type(8)));
typedef float  f32x4  __attribute__((ext_vector_type(4)));
union FragU { __bf16 b[8]; bf16x8 v; };

// ---- module-scope scratch (all fully rewritten every call) ----
__device__ __align__(16) float g_xz [TSTEP*BATCH*G4];      // 8 MB  [t][b][col]
__device__ __align__(16) float g_ht0[UNITS*BATCH];         // h^T [512][64]
__device__ __align__(16) float g_ht1[UNITS*BATCH];
__device__ __align__(16) float g_c0 [BATCH*UNITS];
__device__ __align__(16) float g_c1 [BATCH*UNITS];
__device__ __align__(16) unsigned short g_Ah[BATCH*KFLAT]; // flat hi (bf16) 1 MB
__device__ __align__(16) unsigned short g_Al[BATCH*KFLAT]; // flat lo (bf16) 1 MB
__device__ __align__(16) float g_part[KSPLIT*BATCH*VOCAB]; // 32.8 MB partial logits

__device__ __forceinline__ float sigmoidf_(float x) {
    return 1.0f / (1.0f + expf(-x));
}
__device__ __forceinline__ unsigned short f2bf(float f) {   // fp32 -> bf16 RNE
    unsigned u = __float_as_uint(f);
    return (unsigned short)((u + 0x7fffu + ((u >> 16) & 1u)) >> 16);
}
__device__ __forceinline__ float bf2f(unsigned short h) {
    return __uint_as_float((unsigned)h << 16);
}

// enc_h [64][512] -> g_ht0 [512][64]
__global__ __launch_bounds__(256) void transpose_h_kernel(const float* __restrict__ src)
{
    int i = blockIdx.x * 256 + threadIdx.x;   // 32768
    int b = i >> 9, u = i & 511;
    g_ht0[u*BATCH + b] = src[i];
}

// xz[t][b][col] = bias[col] + emb[inputs[b][t]][:] @ Wx[:,col]
// grid (8, 128) x 256 thr: 8 rows (of 1024) x 256 cols per block.
__global__ __launch_bounds__(256) void xz_kernel(
    const int* __restrict__ inputs, const float* __restrict__ emb,
    const float* __restrict__ Wx, const float* __restrict__ bias)
{
    const int col = blockIdx.x * 256 + threadIdx.x;
    const int r0  = blockIdx.y * 8;
    const float* e[8];
    #pragma unroll
    for (int i = 0; i < 8; ++i) {
        int r = r0 + i, t = r >> 6, b = r & 63;
        e[i] = emb + (size_t)inputs[b*TSTEP + t]*EM;
    }
    float a[8];
    float bb = bias[col];
    #pragma unroll
    for (int i = 0; i < 8; ++i) a[i] = bb;
    #pragma unroll 2
    for (int k = 0; k < EM; ++k) {
        float w = Wx[(size_t)k*G4 + col];
        #pragma unroll
        for (int i = 0; i < 8; ++i) a[i] = fmaf(e[i][k], w, a[i]);
    }
    #pragma unroll
    for (int i = 0; i < 8; ++i)
        g_xz[(size_t)(r0+i)*G4 + col] = a[i];
}

// One LSTM step: z = xz_t + h @ Wh, gates, update c/h.
// grid (32 u-tiles of 16, 16 b-tiles of 4) = 512 blocks x 256 thr (2 blk/CU).
// Block: 64 gate-cols (4 gates x 16 u) x 4 K-quarters (kh = tid>>6).
__global__ __launch_bounds__(256) void lstm_step_kernel(
    const float* __restrict__ Wh, const float* __restrict__ enc_c, int t)
{
    const float* h_in  = (t & 1) ? g_ht1 : g_ht0;
    float*       h_out = (t & 1) ? g_ht0 : g_ht1;
    const float* c_in  = (t == 0) ? enc_c : ((t & 1) ? g_c0 : g_c1);
    float*       c_out = (t & 1) ? g_c1 : g_c0;

    __shared__ float zp[4][64][4];    // [kh][gate*16+ul][b] 4 KB
    const int tid  = threadIdx.x;
    const int ci   = tid & 63, kh = tid >> 6;
    const int gate = ci >> 4, ul = ci & 15;
    const int u0   = blockIdx.x * 16;
    const int b0   = blockIdx.y * 4;
    const int col  = gate*UNITS + u0 + ul;

    float a0, a1, a2, a3;
    if (kh == 0) {
        const float* xz = g_xz + ((size_t)t*BATCH + b0)*G4 + col;
        a0 = xz[0]; a1 = xz[G4]; a2 = xz[2*G4]; a3 = xz[3*G4];
    } else {
        a0 = a1 = a2 = a3 = 0.f;
    }
    const int k0 = kh * 128;
    #pragma unroll 4
    for (int k = k0; k < k0 + 128; ++k) {
        float w = Wh[(size_t)k*G4 + col];
        const float4 hv = *reinterpret_cast<const float4*>(h_in + (size_t)k*BATCH + b0);
        a0 = fmaf(hv.x, w, a0);
        a1 = fmaf(hv.y, w, a1);
        a2 = fmaf(hv.z, w, a2);
        a3 = fmaf(hv.w, w, a3);
    }
    zp[kh][ci][0] = a0; zp[kh][ci][1] = a1;
    zp[kh][ci][2] = a2; zp[kh][ci][3] = a3;
    __syncthreads();

    if (tid < 64) {
        const int bl = tid >> 4, u2 = tid & 15;
        const int b = b0 + bl, u = u0 + u2;
        float zi = zp[0][0*16+u2][bl] + zp[1][0*16+u2][bl] + zp[2][0*16+u2][bl] + zp[3][0*16+u2][bl];
        float zf = zp[0][1*16+u2][bl] + zp[1][1*16+u2][bl] + zp[2][1*16+u2][bl] + zp[3][1*16+u2][bl];
        float zg = zp[0][2*16+u2][bl] + zp[1][2*16+u2][bl] + zp[2][2*16+u2][bl] + zp[3][2*16+u2][bl];
        float zo = zp[0][3*16+u2][bl] + zp[1][3*16+u2][bl] + zp[2][3*16+u2][bl] + zp[3][3*16+u2][bl];
        float c = sigmoidf_(zf) * c_in[(size_t)b*UNITS + u] + sigmoidf_(zi) * sigmoidf_(zg);
        float h = sigmoidf_(zo) * sigmoidf_(c);
        c_out[(size_t)b*UNITS + u] = c;
        h_out[(size_t)u*BATCH + b] = h;
        unsigned short hh = f2bf(h);
        size_t ai = (size_t)b*KFLAT + t*UNITS + u;
        g_Ah[ai] = hh;
        g_Al[ai] = f2bf(h - bf2f(hh));
    }
}

// ---- logits helpers: 2-deep register ping-pong pipeline ----
__device__ __forceinline__ void load_chunk(
    int kb, int r, int n0, const float* __restrict__ Wout,
    FragU ah[4], FragU al[4], float wB[2][8])
{
    #pragma unroll
    for (int ms = 0; ms < 4; ++ms) {
        size_t aoff = (size_t)(ms*16 + r)*KFLAT + kb;
        ah[ms].v = *reinterpret_cast<const bf16x8*>(g_Ah + aoff);
        al[ms].v = *reinterpret_cast<const bf16x8*>(g_Al + aoff);
    }
    #pragma unroll
    for (int nt = 0; nt < 2; ++nt) {
        const float* wp = Wout + (size_t)kb * VOCAB + n0 + nt*16 + r;
        #pragma unroll
        for (int j = 0; j < 8; ++j)
            wB[nt][j] = __builtin_nontemporal_load(wp + (size_t)j * VOCAB);
    }
}

__device__ __forceinline__ void compute_chunk(
    FragU ah[4], FragU al[4], float wB[2][8], f32x4 acc[4][2])
{
    #pragma unroll
    for (int nt = 0; nt < 2; ++nt) {
        FragU bh, bl;
        #pragma unroll
        for (int j = 0; j < 8; ++j) {
            float w = wB[nt][j];
            __bf16 hi = (__bf16)w;          // RNE (v_cvt_pk_bf16_f32)
            bh.b[j] = hi;
            bl.b[j] = (__bf16)(w - (float)hi);
        }
        #pragma unroll
        for (int ms = 0; ms < 4; ++ms)
            acc[ms][nt] = __builtin_amdgcn_mfma_f32_16x16x32_bf16(ah[ms].v, bh.v, acc[ms][nt], 0, 0, 0);
        #pragma unroll
        for (int ms = 0; ms < 4; ++ms)
            acc[ms][nt] = __builtin_amdgcn_mfma_f32_16x16x32_bf16(al[ms].v, bh.v, acc[ms][nt], 0, 0, 0);
        #pragma unroll
        for (int ms = 0; ms < 4; ++ms)
            acc[ms][nt] = __builtin_amdgcn_mfma_f32_16x16x32_bf16(ah[ms].v, bl.v, acc[ms][nt], 0, 0, 0);
    }
}

// Partial logits via bf16x3-split MFMA, software-pipelined (2 chunk buffers).
// grid (250 n-blocks, 4 k-splits) x 256 thr (4 waves). Wave: 64x32 tile.
__global__ __launch_bounds__(256, 3) void logits_mfma_kernel(
    const float* __restrict__ Wout)
{
    const int tid = threadIdx.x;
    const int wv  = tid >> 6, l = tid & 63;
    const int r   = l & 15, g = l >> 4;
    const int g8  = g * 8;
    const int n0  = blockIdx.x * 128 + wv * 32;
    const int k0  = blockIdx.y * KR;

    f32x4 acc[4][2];
    #pragma unroll
    for (int ms = 0; ms < 4; ++ms)
        #pragma unroll
        for (int nt = 0; nt < 2; ++nt)
            acc[ms][nt] = (f32x4){0.f, 0.f, 0.f, 0.f};

    FragU ahA[4], alA[4]; float wA[2][8];
    FragU ahB[4], alB[4]; float wB_[2][8];

    // 64 chunks of K=32; ping-pong: A computes evens, B odds.
    load_chunk(k0 + g8, r, n0, Wout, ahA, alA, wA);
    for (int c = 0; c < 64; c += 2) {
        int c1 = (c+1 < 64) ? c+1 : 63;          // clamp keeps prefetch in-bounds
        load_chunk(k0 + c1*32 + g8, r, n0, Wout, ahB, alB, wB_);
        compute_chunk(ahA, alA, wA, acc);
        int c2 = (c+2 < 64) ? c+2 : 63;
        load_chunk(k0 + c2*32 + g8, r, n0, Wout, ahA, alA, wA);
        compute_chunk(ahB, alB, wB_, acc);
    }

    // write partial: C row = (lane>>4)*4 + reg, col = lane&15
    float* pp = g_part + (size_t)blockIdx.y * BATCH * VOCAB;
    #pragma unroll
    for (int ms = 0; ms < 4; ++ms) {
        #pragma unroll
        for (int nt = 0; nt < 2; ++nt) {
            #pragma unroll
            for (int j = 0; j < 4; ++j) {
                int m = ms*16 + g*4 + j;
                pp[(size_t)m*VOCAB + n0 + nt*16 + r] = acc[ms][nt][j];
            }
        }
    }
}

// Combine K-split partials + bias, then row softmax. One block per row.
__global__ __launch_bounds__(1024) void combine_softmax_kernel(
    const float* __restrict__ bout, float* __restrict__ out)
{
    const int m = blockIdx.x;
    const int tid = threadIdx.x;
    const int wid = tid >> 6, lane = tid & 63;
    __shared__ float red[16];
    float* po = out + (size_t)m * VOCAB;

    float mx = -3.0e38f;
    for (int n = tid; n < VOCAB; n += 1024) {
        float v = g_part[(size_t)0*BATCH*VOCAB + (size_t)m*VOCAB + n]
                + g_part[(size_t)1*BATCH*VOCAB + (size_t)m*VOCAB + n]
                + g_part[(size_t)2*BATCH*VOCAB + (size_t)m*VOCAB + n]
                + g_part[(size_t)3*BATCH*VOCAB + (size_t)m*VOCAB + n]
                + bout[n];
        po[n] = v;
        mx = fmaxf(mx, v);
    }
    #pragma unroll
    for (int o = 32; o; o >>= 1) mx = fmaxf(mx, __shfl_xor(mx, o));
    if (lane == 0) red[wid] = mx;
    __syncthreads();
    mx = red[0];
    #pragma unroll
    for (int i = 1; i < 16; ++i) mx = fmaxf(mx, red[i]);
    __syncthreads();

    float s = 0.f;
    for (int n = tid; n < VOCAB; n += 1024) {
        float e = expf(po[n] - mx);
        po[n] = e;
        s += e;
    }
    #pragma unroll
    for (int o = 32; o; o >>= 1) s += __shfl_xor(s, o);
    if (lane == 0) red[wid] = s;
    __syncthreads();
    s = 0.f;
    #pragma unroll
    for (int i = 0; i < 16; ++i) s += red[i];
    float inv = 1.0f / s;

    for (int n = tid; n < VOCAB; n += 1024) po[n] *= inv;
}

extern "C" void kernel_launch(void* const* d_in, const int* in_sizes, int n_in,
                              void* d_out, int out_size, void* d_ws, size_t ws_size,
                              hipStream_t stream) {
    const int*   inputs = (const int*)  d_in[0];
    const float* enc_h  = (const float*)d_in[1];
    const float* enc_c  = (const float*)d_in[2];
    const float* emb    = (const float*)d_in[3];
    const float* Wx     = (const float*)d_in[4];
    const float* Wh     = (const float*)d_in[5];
    const float* bvec   = (const float*)d_in[6];
    const float* Wout   = (const float*)d_in[7];
    const float* bout   = (const float*)d_in[8];
    float* out = (float*)d_out;
    (void)d_ws; (void)ws_size; (void)in_sizes; (void)n_in; (void)out_size;

    transpose_h_kernel<<<128, 256, 0, stream>>>(enc_h);
    xz_kernel<<<dim3(8, 128), 256, 0, stream>>>(inputs, emb, Wx, bvec);

    for (int t = 0; t < TSTEP; ++t)
        lstm_step_kernel<<<dim3(32, 16), 256, 0, stream>>>(Wh, enc_c, t);

    logits_mfma_kernel<<<dim3(250, KSPLIT), 256, 0, stream>>>(Wout);
    combine_softmax_kernel<<<64, 1024, 0, stream>>>(bout, out);
}